// Round 20
// baseline (188.618 us; speedup 1.0000x reference)
//
#include <hip/hip_runtime.h>

#define NN 100000
#define NE 2400000
#define NB 391              // buckets of 256 dst nodes
#define CAP 6912            // per-bucket edge capacity (mean 6144, +9.8 sigma)
#define EPB 8192            // edges per sort block
#define NBLK2 ((NE + EPB - 1) / EPB)   // 293

__device__ __forceinline__ int wexscan(int v, int lane) {
    int x = v;
#pragma unroll
    for (int off = 1; off < 64; off <<= 1) {
        int t = __shfl_up(x, off, 64);
        x += (lane >= off) ? t : 0;
    }
    return x - v;            // exclusive prefix within wave64
}

// ---------------- pass 1: per-block bucket histogram (no global atomics) ----------------
__global__ __launch_bounds__(1024) void k_hist(const int* __restrict__ ei,
        int* __restrict__ bh) {
    __shared__ int hist[NB];
    int tid = threadIdx.x;
    for (int i = tid; i < NB; i += 1024) hist[i] = 0;
    __syncthreads();
    int base_e = blockIdx.x * EPB + tid * 8;
    if (base_e + 8 <= NE) {                  // NE%8==0: all-or-nothing per thread
        int4 da = *(const int4*)(ei + NE + base_e);
        int4 db = *(const int4*)(ei + NE + base_e + 4);
        atomicAdd(&hist[da.x >> 8], 1); atomicAdd(&hist[da.y >> 8], 1);
        atomicAdd(&hist[da.z >> 8], 1); atomicAdd(&hist[da.w >> 8], 1);
        atomicAdd(&hist[db.x >> 8], 1); atomicAdd(&hist[db.y >> 8], 1);
        atomicAdd(&hist[db.z >> 8], 1); atomicAdd(&hist[db.w >> 8], 1);
    }
    __syncthreads();
    for (int i = tid; i < NB; i += 1024) bh[blockIdx.x * NB + i] = hist[i];
}

// ---------------- pass 2: per-bucket scan over blocks -> exact offsets ----------------
__global__ __launch_bounds__(256) void k_offscan(int* __restrict__ bh,
        int* __restrict__ tot) {
    __shared__ int wsum[4];
    int b = blockIdx.x, tid = threadIdx.x;
    int lane = tid & 63, wid = tid >> 6;
    int carry = 0;
#pragma unroll
    for (int r = 0; r < 2; ++r) {            // ceil(293/256)=2 rounds
        int blk = r * 256 + tid;
        int v = (blk < NBLK2) ? bh[blk * NB + b] : 0;
        int ex = wexscan(v, lane);
        if (lane == 63) wsum[wid] = ex + v;
        __syncthreads();
        int woff = 0, rt = 0;
#pragma unroll
        for (int i = 0; i < 4; ++i) {
            woff += (i < wid) ? wsum[i] : 0;
            rt += wsum[i];
        }
        if (blk < NBLK2) bh[blk * NB + b] = b * CAP + carry + woff + ex;
        carry += rt;
        __syncthreads();
    }
    if (tid == 0) tot[b] = carry;
}

// ---------------- pass 3: scatter to bucket regions (no global atomics) ----------------
__global__ __launch_bounds__(1024) void k_scatter2(const int* __restrict__ ei,
        const int* __restrict__ bh, int* __restrict__ binned) {
    __shared__ int hist[NB], lbase[NB], myb[NB];
    __shared__ int stage[EPB];
    __shared__ unsigned short stageb[EPB];
    __shared__ int wsum[16];
    int tid = threadIdx.x;
    for (int i = tid; i < NB; i += 1024) {
        hist[i] = 0;
        myb[i] = bh[blockIdx.x * NB + i];    // precomputed exact base
    }
    __syncthreads();
    int base_e = blockIdx.x * EPB + tid * 8;
    int pk[8], bn[8], rk[8];
    if (base_e + 8 <= NE) {
        const int4* s4 = (const int4*)(ei + base_e);
        const int4* d4 = (const int4*)(ei + NE + base_e);
        int4 sa = s4[0], sb = s4[1], da = d4[0], db = d4[1];
        int ss[8] = {sa.x, sa.y, sa.z, sa.w, sb.x, sb.y, sb.z, sb.w};
        int dd[8] = {da.x, da.y, da.z, da.w, db.x, db.y, db.z, db.w};
#pragma unroll
        for (int k = 0; k < 8; ++k) {
            bn[k] = dd[k] >> 8;
            pk[k] = ss[k] | ((dd[k] & 255) << 17);
            rk[k] = atomicAdd(&hist[bn[k]], 1);      // LDS rank only
        }
    } else {
#pragma unroll
        for (int k = 0; k < 8; ++k) bn[k] = -1;
    }
    __syncthreads();
    int lane = tid & 63, wid = tid >> 6;
    int v = (tid < NB) ? hist[tid] : 0;
    int ex = wexscan(v, lane);
    if (lane == 63) wsum[wid] = ex + v;
    __syncthreads();
    int woff = 0, tot = 0;
#pragma unroll
    for (int i = 0; i < 16; ++i) {
        int s = wsum[i];
        woff += (i < wid) ? s : 0;
        tot += s;
    }
    ex += woff;
    if (tid < NB) lbase[tid] = ex;
    __syncthreads();
#pragma unroll
    for (int k = 0; k < 8; ++k) {
        if (bn[k] >= 0) {
            int slot = lbase[bn[k]] + rk[k];
            stage[slot] = pk[k];
            stageb[slot] = (unsigned short)bn[k];
        }
    }
    __syncthreads();
    for (int j = tid; j < tot; j += 1024) {
        int b = stageb[j];
        binned[myb[b] + (j - lbase[b])] = stage[j];
    }
}

// ---------------- per-bucket degree count -> rsp, dinv, prescaled xs ----------------
__global__ __launch_bounds__(256) void k_csr_count(const int* __restrict__ binned,
        const int* __restrict__ tot, const float* __restrict__ x,
        int* __restrict__ rsp, float* __restrict__ dinv, float2* __restrict__ xs) {
    __shared__ int cnt[256];
    __shared__ int wsum[4];
    int tid = threadIdx.x, b = blockIdx.x;
    int base = b * CAP, n = tot[b];
    cnt[tid] = 0;
    __syncthreads();
    int n4 = n >> 2;
    const int4* b4 = (const int4*)(binned + base);
    for (int j = tid; j < n4; j += 256) {
        int4 w = b4[j];
        atomicAdd(&cnt[(w.x >> 17) & 255], 1);
        atomicAdd(&cnt[(w.y >> 17) & 255], 1);
        atomicAdd(&cnt[(w.z >> 17) & 255], 1);
        atomicAdd(&cnt[(w.w >> 17) & 255], 1);
    }
    for (int j = (n4 << 2) + tid; j < n; j += 256)
        atomicAdd(&cnt[(binned[base + j] >> 17) & 255], 1);
    __syncthreads();
    int deg = cnt[tid];
    int lane = tid & 63, wid = tid >> 6;
    int ex = wexscan(deg, lane);
    if (lane == 63) wsum[wid] = ex + deg;
    __syncthreads();
    int woff = 0;
#pragma unroll
    for (int i = 0; i < 4; ++i) woff += (i < wid) ? wsum[i] : 0;
    ex += woff;
    int node = (b << 8) + tid;
    if (node < NN) {
        rsp[node] = ((base + ex) << 8) | deg;            // packed start|deg
        float di = rsqrtf((float)(deg + 1));             // +1 self-loop
        dinv[node] = di;
        float2 xv = ((const float2*)x)[node];
        xs[node] = make_float2(di * xv.x, di * xv.y);
    }
}

// ---------------- csr placement, then per-node register walk -> At ----------------
// xs fully written by k_csr_count (previous launch) -> safe to read any node here.
__global__ __launch_bounds__(256) void k_csr_place(const int* __restrict__ binned,
        const int* __restrict__ tot, const int* __restrict__ rsp,
        const float2* __restrict__ xs, const float* __restrict__ dinv,
        int* __restrict__ csr, float4* __restrict__ At) {
    __shared__ int cur2[256];
    int tid = threadIdx.x, b = blockIdx.x;
    int base = b * CAP, n = tot[b];
    int node = (b << 8) + tid;
    int rp = (node < NN) ? rsp[node] : 0;
    cur2[tid] = (node < NN) ? ((rp >> 8) - base) : 0;
    __syncthreads();
    int n4 = n >> 2;
    const int4* b4 = (const int4*)(binned + base);
    for (int j = tid; j < n4; j += 256) {
        int4 w = b4[j];
        int p0 = atomicAdd(&cur2[(w.x >> 17) & 255], 1); csr[base + p0] = w.x & 0x1FFFF;
        int p1 = atomicAdd(&cur2[(w.y >> 17) & 255], 1); csr[base + p1] = w.y & 0x1FFFF;
        int p2 = atomicAdd(&cur2[(w.z >> 17) & 255], 1); csr[base + p2] = w.z & 0x1FFFF;
        int p3 = atomicAdd(&cur2[(w.w >> 17) & 255], 1); csr[base + p3] = w.w & 0x1FFFF;
    }
    for (int j = (n4 << 2) + tid; j < n; j += 256) {
        int w = binned[base + j];
        int p = atomicAdd(&cur2[(w >> 17) & 255], 1);
        csr[base + p] = w & 0x1FFFF;
    }
    __syncthreads();                          // csr slice complete (in-block, L2-hot)
    if (node < NN) {
        int beg = rp >> 8, deg = rp & 255;
        float ax = 0.f, ay = 0.f;
        int e = beg, end = beg + deg;
        for (; e + 4 <= end; e += 4) {
            int s0 = csr[e], s1 = csr[e + 1], s2 = csr[e + 2], s3 = csr[e + 3];
            float2 v0 = xs[s0], v1 = xs[s1], v2 = xs[s2], v3 = xs[s3];
            ax += (v0.x + v1.x) + (v2.x + v3.x);
            ay += (v0.y + v1.y) + (v2.y + v3.y);
        }
        for (; e < end; ++e) { float2 vv = xs[csr[e]]; ax += vv.x; ay += vv.y; }
        float di = dinv[node];
        float2 xn = xs[node];                 // self-loop term
        At[node] = make_float4(di * (ax + xn.x), di * (ay + xn.y), di, 0.f);
    }
}

// ---------------- layer-2 gather: R13-exact fly (late barrier, fixed-32 tail) ----------------
__global__ __launch_bounds__(256) void k_gather_fly(const float4* __restrict__ At,
        const int* __restrict__ rsp, const int* __restrict__ csr,
        const float* __restrict__ W1, const float* __restrict__ b1,
        const float* __restrict__ W2, const float* __restrict__ b2,
        const float* __restrict__ W3, float* __restrict__ h3) {
    __shared__ float WsT[32 * 36];            // transposed W2, row stride 36 (16B-aligned)
    __shared__ float accS[256];
    __shared__ float4 stage[8][32];
    int tid = threadIdx.x;
    for (int j = tid; j < 1024; j += 256) {
        int k = j >> 5, fo = j & 31;
        WsT[fo * 36 + k] = W2[j];             // WsT[f][k] = W2[k][f]
    }
    int g = tid >> 5, f = tid & 31;
    int node = blockIdx.x * 8 + g;                         // grid*8 == NN exactly
    float w0f = W1[f], w1f = W1[32 + f], bf = b1[f];
    float4 an = At[node];
    int r = rsp[node];
    float di = an.z;
    float vs = fmaf(an.y, w1f, fmaf(an.x, w0f, bf));
    float acc0 = di * fmaxf(vs, 0.f), acc1 = 0.f;          // self-loop
    int beg = r >> 8, deg = r & 255;
    float4* st = &stage[g][0];
    for (int b0 = 0; b0 < deg; b0 += 32) {
        float4 a = make_float4(0.f, 0.f, 0.f, 0.f);        // az=0 pads contribute 0
        if (b0 + f < deg) a = At[csr[beg + b0 + f]];
        st[f] = a;                                         // in-wave exchange,
        __asm__ __volatile__("" ::: "memory");             // DS pipe is in-order
#pragma unroll
        for (int j = 0; j < 32; j += 2) {
            float4 e0 = st[j], e1 = st[j + 1];             // same-addr broadcast reads
            float v0 = fmaf(e0.y, w1f, fmaf(e0.x, w0f, bf));
            acc0 = fmaf(e0.z, fmaxf(v0, 0.f), acc0);
            float v1 = fmaf(e1.y, w1f, fmaf(e1.x, w0f, bf));
            acc1 = fmaf(e1.z, fmaxf(v1, 0.f), acc1);
        }
        __asm__ __volatile__("" ::: "memory");
    }
    accS[tid] = di * (acc0 + acc1);           // agg2 = di * (sum + self)
    __syncthreads();                          // orders WsT staging vs reads (late barrier)
    int n0 = tid & 224;                       // group base
    float sum = b2[f];
    const float* wrow = &WsT[f * 36];
#pragma unroll
    for (int k = 0; k < 32; k += 4) {         // b128 reads: 16 DS reads total
        float4 a4 = *(const float4*)&accS[n0 + k];   // group-broadcast, aligned
        float4 w4 = *(const float4*)&wrow[k];        // lane-private row, aligned
        sum = fmaf(a4.x, w4.x, sum);
        sum = fmaf(a4.y, w4.y, sum);
        sum = fmaf(a4.z, w4.z, sum);
        sum = fmaf(a4.w, w4.w, sum);
    }
    float h2 = fmaxf(sum, 0.f);
    float v = di * h2 * W3[f];
#pragma unroll
    for (int off = 16; off > 0; off >>= 1) v += __shfl_down(v, off, 32);
    if (f == 0) h3[node] = v;
}

// ---------------- width-1 gather -> out ----------------
__global__ __launch_bounds__(256) void k_gather_out(const float* __restrict__ hs,
        const int* __restrict__ rsp, const int* __restrict__ csr,
        const float* __restrict__ dinv, const float* __restrict__ bias,
        float* __restrict__ out) {
    int node = blockIdx.x * 256 + threadIdx.x;
    if (node >= NN) return;
    int r = rsp[node];
    int beg = r >> 8, end = beg + (r & 255);
    float acc = hs[node];
    int e = beg;
    for (; e + 4 <= end; e += 4) {
        int s0 = csr[e], s1 = csr[e + 1], s2 = csr[e + 2], s3 = csr[e + 3];
        acc += (hs[s0] + hs[s1]) + (hs[s2] + hs[s3]);
    }
    for (; e < end; ++e) acc += hs[csr[e]];
    out[node] = dinv[node] * acc + bias[0];
}

extern "C" void kernel_launch(void* const* d_in, const int* in_sizes, int n_in,
                              void* d_out, int out_size, void* d_ws, size_t ws_size,
                              hipStream_t stream) {
    const float* x  = (const float*)d_in[0];
    const int*   ei = (const int*)d_in[1];   // [2, NE] int32
    const float* W1 = (const float*)d_in[2];
    const float* b1 = (const float*)d_in[3];
    const float* W2 = (const float*)d_in[4];
    const float* b2 = (const float*)d_in[5];
    const float* W3 = (const float*)d_in[6];
    const float* b3 = (const float*)d_in[7];
    float* out = (float*)d_out;

    char* w = (char*)d_ws;
    float4* At    = (float4*)w; w += NN * 16;           // 16B-aligned first, 1.6 MB
    float2* xs    = (float2*)w; w += NN * 8;
    int*   bh     = (int*)w;    w += NBLK2 * NB * 4;    // 0.46 MB block-hist/offsets
    int*   tot    = (int*)w;    w += NB * 4;
    int*   rsp    = (int*)w;    w += NN * 4;
    float* dinv   = (float*)w;  w += NN * 4;
    int*   binned = (int*)w;    w += NB * CAP * 4;      // 10.8 MB
    int*   csr    = (int*)w;    w += NB * CAP * 4;      // 10.8 MB
    float* h3     = (float*)w;  w += NN * 4;

    const int G_N = (NN + 255) / 256;        // 391
    const int G_G = NN / 8;                  // 12500 (exact)

    k_hist<<<NBLK2, 1024, 0, stream>>>(ei, bh);
    k_offscan<<<NB, 256, 0, stream>>>(bh, tot);
    k_scatter2<<<NBLK2, 1024, 0, stream>>>(ei, bh, binned);
    k_csr_count<<<NB, 256, 0, stream>>>(binned, tot, x, rsp, dinv, xs);
    k_csr_place<<<NB, 256, 0, stream>>>(binned, tot, rsp, xs, dinv, csr, At);
    k_gather_fly<<<G_G, 256, 0, stream>>>(At, rsp, csr, W1, b1, W2, b2, W3, h3);
    k_gather_out<<<G_N, 256, 0, stream>>>(h3, rsp, csr, dinv, b3, out);
}

// Round 21
// 186.882 us; speedup vs baseline: 1.0093x; 1.0093x over previous
//
#include <hip/hip_runtime.h>

#define NN 100000
#define NE 2400000
#define NB 391              // buckets of 256 dst nodes
#define CAP 6912            // per-bucket edge capacity (mean 6144, +9.8 sigma)
#define EPB 4096            // edges per sort block
#define NBLK2 ((NE + EPB - 1) / EPB)   // 586

__device__ __forceinline__ int wexscan(int v, int lane) {
    int x = v;
#pragma unroll
    for (int off = 1; off < 64; off <<= 1) {
        int t = __shfl_up(x, off, 64);
        x += (lane >= off) ? t : 0;
    }
    return x - v;            // exclusive prefix within wave64
}

// ---------------- pass 1: per-block bucket histogram (no global atomics) ----------------
__global__ __launch_bounds__(512) void k_hist(const int* __restrict__ ei,
        int* __restrict__ bh) {
    __shared__ int hist[NB];
    int tid = threadIdx.x;
    for (int i = tid; i < NB; i += 512) hist[i] = 0;
    __syncthreads();
    int base_e = blockIdx.x * EPB + tid * 8;
    if (base_e + 8 <= NE) {                  // NE%8==0: all-or-nothing per thread
        int4 da = *(const int4*)(ei + NE + base_e);
        int4 db = *(const int4*)(ei + NE + base_e + 4);
        atomicAdd(&hist[da.x >> 8], 1); atomicAdd(&hist[da.y >> 8], 1);
        atomicAdd(&hist[da.z >> 8], 1); atomicAdd(&hist[da.w >> 8], 1);
        atomicAdd(&hist[db.x >> 8], 1); atomicAdd(&hist[db.y >> 8], 1);
        atomicAdd(&hist[db.z >> 8], 1); atomicAdd(&hist[db.w >> 8], 1);
    }
    __syncthreads();
    for (int i = tid; i < NB; i += 512) bh[blockIdx.x * NB + i] = hist[i];
}

// ---------------- pass 2: per-bucket scan over blocks -> exact offsets ----------------
__global__ __launch_bounds__(256) void k_offscan(int* __restrict__ bh,
        int* __restrict__ tot) {
    __shared__ int wsum[4];
    int b = blockIdx.x, tid = threadIdx.x;
    int lane = tid & 63, wid = tid >> 6;
    int carry = 0;
#pragma unroll
    for (int r = 0; r < 3; ++r) {            // ceil(586/256)=3 rounds
        int blk = r * 256 + tid;
        int v = (blk < NBLK2) ? bh[blk * NB + b] : 0;
        int ex = wexscan(v, lane);
        if (lane == 63) wsum[wid] = ex + v;
        __syncthreads();
        int woff = 0, rt = 0;
#pragma unroll
        for (int i = 0; i < 4; ++i) {
            woff += (i < wid) ? wsum[i] : 0;
            rt += wsum[i];
        }
        if (blk < NBLK2) bh[blk * NB + b] = b * CAP + carry + woff + ex;
        carry += rt;
        __syncthreads();
    }
    if (tid == 0) tot[b] = carry;
}

// ---------------- pass 3: scatter to bucket regions (no global atomics) ----------------
__global__ __launch_bounds__(512) void k_scatter2(const int* __restrict__ ei,
        const int* __restrict__ bh, int* __restrict__ binned) {
    __shared__ int hist[NB], lbase[NB], myb[NB];
    __shared__ int stage[EPB];
    __shared__ unsigned short stageb[EPB];
    __shared__ int wsum[8];
    int tid = threadIdx.x;
    for (int i = tid; i < NB; i += 512) {
        hist[i] = 0;
        myb[i] = bh[blockIdx.x * NB + i];    // precomputed exact base
    }
    __syncthreads();
    int base_e = blockIdx.x * EPB + tid * 8;
    int pk[8], bn[8], rk[8];
    if (base_e + 8 <= NE) {
        const int4* s4 = (const int4*)(ei + base_e);
        const int4* d4 = (const int4*)(ei + NE + base_e);
        int4 sa = s4[0], sb = s4[1], da = d4[0], db = d4[1];
        int ss[8] = {sa.x, sa.y, sa.z, sa.w, sb.x, sb.y, sb.z, sb.w};
        int dd[8] = {da.x, da.y, da.z, da.w, db.x, db.y, db.z, db.w};
#pragma unroll
        for (int k = 0; k < 8; ++k) {
            bn[k] = dd[k] >> 8;
            pk[k] = ss[k] | ((dd[k] & 255) << 17);
            rk[k] = atomicAdd(&hist[bn[k]], 1);      // LDS rank only
        }
    } else {
#pragma unroll
        for (int k = 0; k < 8; ++k) bn[k] = -1;
    }
    __syncthreads();
    int lane = tid & 63, wid = tid >> 6;
    int v = (tid < NB) ? hist[tid] : 0;
    int ex = wexscan(v, lane);
    if (lane == 63) wsum[wid] = ex + v;
    __syncthreads();
    int woff = 0, tot = 0;
#pragma unroll
    for (int i = 0; i < 8; ++i) {
        int s = wsum[i];
        woff += (i < wid) ? s : 0;
        tot += s;
    }
    ex += woff;
    if (tid < NB) lbase[tid] = ex;
    __syncthreads();
#pragma unroll
    for (int k = 0; k < 8; ++k) {
        if (bn[k] >= 0) {
            int slot = lbase[bn[k]] + rk[k];
            stage[slot] = pk[k];
            stageb[slot] = (unsigned short)bn[k];
        }
    }
    __syncthreads();
    for (int j = tid; j < tot; j += 512) {
        int b = stageb[j];
        binned[myb[b] + (j - lbase[b])] = stage[j];
    }
}

// ---------------- per-bucket degree count -> rsp, dinv, prescaled xs ----------------
__global__ __launch_bounds__(256) void k_csr_count(const int* __restrict__ binned,
        const int* __restrict__ tot, const float* __restrict__ x,
        int* __restrict__ rsp, float* __restrict__ dinv, float2* __restrict__ xs) {
    __shared__ int cnt[256];
    __shared__ int wsum[4];
    int tid = threadIdx.x, b = blockIdx.x;
    int base = b * CAP, n = tot[b];
    cnt[tid] = 0;
    __syncthreads();
    int n4 = n >> 2;
    const int4* b4 = (const int4*)(binned + base);
    for (int j = tid; j < n4; j += 256) {
        int4 w = b4[j];
        atomicAdd(&cnt[(w.x >> 17) & 255], 1);
        atomicAdd(&cnt[(w.y >> 17) & 255], 1);
        atomicAdd(&cnt[(w.z >> 17) & 255], 1);
        atomicAdd(&cnt[(w.w >> 17) & 255], 1);
    }
    for (int j = (n4 << 2) + tid; j < n; j += 256)
        atomicAdd(&cnt[(binned[base + j] >> 17) & 255], 1);
    __syncthreads();
    int deg = cnt[tid];
    int lane = tid & 63, wid = tid >> 6;
    int ex = wexscan(deg, lane);
    if (lane == 63) wsum[wid] = ex + deg;
    __syncthreads();
    int woff = 0;
#pragma unroll
    for (int i = 0; i < 4; ++i) woff += (i < wid) ? wsum[i] : 0;
    ex += woff;
    int node = (b << 8) + tid;
    if (node < NN) {
        rsp[node] = ((base + ex) << 8) | deg;            // packed start|deg
        float di = rsqrtf((float)(deg + 1));             // +1 self-loop
        dinv[node] = di;
        float2 xv = ((const float2*)x)[node];
        xs[node] = make_float2(di * xv.x, di * xv.y);
    }
}

// ---------------- csr placement, then per-node register walk -> At ----------------
// xs fully written by k_csr_count (previous launch) -> safe to read any node here.
__global__ __launch_bounds__(256) void k_csr_place(const int* __restrict__ binned,
        const int* __restrict__ tot, const int* __restrict__ rsp,
        const float2* __restrict__ xs, const float* __restrict__ dinv,
        int* __restrict__ csr, float4* __restrict__ At) {
    __shared__ int cur2[256];
    int tid = threadIdx.x, b = blockIdx.x;
    int base = b * CAP, n = tot[b];
    int node = (b << 8) + tid;
    int rp = (node < NN) ? rsp[node] : 0;
    cur2[tid] = (node < NN) ? ((rp >> 8) - base) : 0;
    __syncthreads();
    int n4 = n >> 2;
    const int4* b4 = (const int4*)(binned + base);
    for (int j = tid; j < n4; j += 256) {
        int4 w = b4[j];
        int p0 = atomicAdd(&cur2[(w.x >> 17) & 255], 1); csr[base + p0] = w.x & 0x1FFFF;
        int p1 = atomicAdd(&cur2[(w.y >> 17) & 255], 1); csr[base + p1] = w.y & 0x1FFFF;
        int p2 = atomicAdd(&cur2[(w.z >> 17) & 255], 1); csr[base + p2] = w.z & 0x1FFFF;
        int p3 = atomicAdd(&cur2[(w.w >> 17) & 255], 1); csr[base + p3] = w.w & 0x1FFFF;
    }
    for (int j = (n4 << 2) + tid; j < n; j += 256) {
        int w = binned[base + j];
        int p = atomicAdd(&cur2[(w >> 17) & 255], 1);
        csr[base + p] = w & 0x1FFFF;
    }
    __syncthreads();                          // csr slice complete (in-block, L2-hot)
    if (node < NN) {
        int beg = rp >> 8, deg = rp & 255;
        float ax = 0.f, ay = 0.f;
        int e = beg, end = beg + deg;
        for (; e + 4 <= end; e += 4) {
            int s0 = csr[e], s1 = csr[e + 1], s2 = csr[e + 2], s3 = csr[e + 3];
            float2 v0 = xs[s0], v1 = xs[s1], v2 = xs[s2], v3 = xs[s3];
            ax += (v0.x + v1.x) + (v2.x + v3.x);
            ay += (v0.y + v1.y) + (v2.y + v3.y);
        }
        for (; e < end; ++e) { float2 vv = xs[csr[e]]; ax += vv.x; ay += vv.y; }
        float di = dinv[node];
        float2 xn = xs[node];                 // self-loop term
        At[node] = make_float4(di * (ax + xn.x), di * (ay + xn.y), di, 0.f);
    }
}

// ---------------- layer-2 gather: R13-exact fly (late barrier, fixed-32 tail) ----------------
__global__ __launch_bounds__(256) void k_gather_fly(const float4* __restrict__ At,
        const int* __restrict__ rsp, const int* __restrict__ csr,
        const float* __restrict__ W1, const float* __restrict__ b1,
        const float* __restrict__ W2, const float* __restrict__ b2,
        const float* __restrict__ W3, float* __restrict__ h3) {
    __shared__ float WsT[32 * 36];            // transposed W2, row stride 36 (16B-aligned)
    __shared__ float accS[256];
    __shared__ float4 stage[8][32];
    int tid = threadIdx.x;
    for (int j = tid; j < 1024; j += 256) {
        int k = j >> 5, fo = j & 31;
        WsT[fo * 36 + k] = W2[j];             // WsT[f][k] = W2[k][f]
    }
    int g = tid >> 5, f = tid & 31;
    int node = blockIdx.x * 8 + g;                         // grid*8 == NN exactly
    float w0f = W1[f], w1f = W1[32 + f], bf = b1[f];
    float4 an = At[node];
    int r = rsp[node];
    float di = an.z;
    float vs = fmaf(an.y, w1f, fmaf(an.x, w0f, bf));
    float acc0 = di * fmaxf(vs, 0.f), acc1 = 0.f;          // self-loop
    int beg = r >> 8, deg = r & 255;
    float4* st = &stage[g][0];
    for (int b0 = 0; b0 < deg; b0 += 32) {
        float4 a = make_float4(0.f, 0.f, 0.f, 0.f);        // az=0 pads contribute 0
        if (b0 + f < deg) a = At[csr[beg + b0 + f]];
        st[f] = a;                                         // in-wave exchange,
        __asm__ __volatile__("" ::: "memory");             // DS pipe is in-order
#pragma unroll
        for (int j = 0; j < 32; j += 2) {
            float4 e0 = st[j], e1 = st[j + 1];             // same-addr broadcast reads
            float v0 = fmaf(e0.y, w1f, fmaf(e0.x, w0f, bf));
            acc0 = fmaf(e0.z, fmaxf(v0, 0.f), acc0);
            float v1 = fmaf(e1.y, w1f, fmaf(e1.x, w0f, bf));
            acc1 = fmaf(e1.z, fmaxf(v1, 0.f), acc1);
        }
        __asm__ __volatile__("" ::: "memory");
    }
    accS[tid] = di * (acc0 + acc1);           // agg2 = di * (sum + self)
    __syncthreads();                          // orders WsT staging vs reads (late barrier)
    int n0 = tid & 224;                       // group base
    float sum = b2[f];
    const float* wrow = &WsT[f * 36];
#pragma unroll
    for (int k = 0; k < 32; k += 4) {         // b128 reads: 16 DS reads total
        float4 a4 = *(const float4*)&accS[n0 + k];   // group-broadcast, aligned
        float4 w4 = *(const float4*)&wrow[k];        // lane-private row, aligned
        sum = fmaf(a4.x, w4.x, sum);
        sum = fmaf(a4.y, w4.y, sum);
        sum = fmaf(a4.z, w4.z, sum);
        sum = fmaf(a4.w, w4.w, sum);
    }
    float h2 = fmaxf(sum, 0.f);
    float v = di * h2 * W3[f];
#pragma unroll
    for (int off = 16; off > 0; off >>= 1) v += __shfl_down(v, off, 32);
    if (f == 0) h3[node] = v;
}

// ---------------- width-1 gather -> out ----------------
__global__ __launch_bounds__(256) void k_gather_out(const float* __restrict__ hs,
        const int* __restrict__ rsp, const int* __restrict__ csr,
        const float* __restrict__ dinv, const float* __restrict__ bias,
        float* __restrict__ out) {
    int node = blockIdx.x * 256 + threadIdx.x;
    if (node >= NN) return;
    int r = rsp[node];
    int beg = r >> 8, end = beg + (r & 255);
    float acc = hs[node];
    int e = beg;
    for (; e + 4 <= end; e += 4) {
        int s0 = csr[e], s1 = csr[e + 1], s2 = csr[e + 2], s3 = csr[e + 3];
        acc += (hs[s0] + hs[s1]) + (hs[s2] + hs[s3]);
    }
    for (; e < end; ++e) acc += hs[csr[e]];
    out[node] = dinv[node] * acc + bias[0];
}

extern "C" void kernel_launch(void* const* d_in, const int* in_sizes, int n_in,
                              void* d_out, int out_size, void* d_ws, size_t ws_size,
                              hipStream_t stream) {
    const float* x  = (const float*)d_in[0];
    const int*   ei = (const int*)d_in[1];   // [2, NE] int32
    const float* W1 = (const float*)d_in[2];
    const float* b1 = (const float*)d_in[3];
    const float* W2 = (const float*)d_in[4];
    const float* b2 = (const float*)d_in[5];
    const float* W3 = (const float*)d_in[6];
    const float* b3 = (const float*)d_in[7];
    float* out = (float*)d_out;

    char* w = (char*)d_ws;
    float4* At    = (float4*)w; w += NN * 16;           // 16B-aligned first, 1.6 MB
    float2* xs    = (float2*)w; w += NN * 8;
    int*   bh     = (int*)w;    w += NBLK2 * NB * 4;    // 0.9 MB block-hist/offsets
    int*   tot    = (int*)w;    w += NB * 4;
    int*   rsp    = (int*)w;    w += NN * 4;
    float* dinv   = (float*)w;  w += NN * 4;
    int*   binned = (int*)w;    w += NB * CAP * 4;      // 10.8 MB
    int*   csr    = (int*)w;    w += NB * CAP * 4;      // 10.8 MB
    float* h3     = (float*)w;  w += NN * 4;

    const int G_N = (NN + 255) / 256;        // 391
    const int G_G = NN / 8;                  // 12500 (exact)

    k_hist<<<NBLK2, 512, 0, stream>>>(ei, bh);
    k_offscan<<<NB, 256, 0, stream>>>(bh, tot);
    k_scatter2<<<NBLK2, 512, 0, stream>>>(ei, bh, binned);
    k_csr_count<<<NB, 256, 0, stream>>>(binned, tot, x, rsp, dinv, xs);
    k_csr_place<<<NB, 256, 0, stream>>>(binned, tot, rsp, xs, dinv, csr, At);
    k_gather_fly<<<G_G, 256, 0, stream>>>(At, rsp, csr, W1, b1, W2, b2, W3, h3);
    k_gather_out<<<G_N, 256, 0, stream>>>(h3, rsp, csr, dinv, b3, out);
}